// Round 9
// baseline (514.881 us; speedup 1.0000x reference)
//
#include <hip/hip_runtime.h>

// ---------------------------------------------------------------------------
// ATFA: dual-axis conv-attention, MI355X fp16-MFMA implementation.
// Round 9: conv_qkv = m201-faithful 8-phase/2-tile pipeline: BM=BN=256,
// 8 waves (wave 128x64), K-split half-tile staging into [256][32] subbufs,
// counted vmcnt(4) twice per K-tile (never 0 in steady state), 16-MFMA
// phases with setprio + sched_barrier pins, B-frags register-cached.
// Also: prep_w -> LDS-transposed (coalesced both sides); vf memset ->
// targeted pad-zero kernel. attn/conv_final/prep_x = round-7/8.
// ---------------------------------------------------------------------------

typedef _Float16 f16;
typedef _Float16 f16x8 __attribute__((ext_vector_type(8)));
typedef float    f32x4 __attribute__((ext_vector_type(4)));

#define B_   2
#define T_   249
#define F_   64
#define TP   251     // T + 2 (padded)
#define FP   66      // F + 2 (padded)
#define PIXB (T_*F_) // 15936 pixels per batch
#define NPIX (B_*PIXB)
#define LPAD 256     // padded attention length for the T-axis heads
#define XPOS (B_*TP*FP)   // 33132 padded positions

static constexpr size_t FUSED_BYTES = (size_t)B_*TP*FP*768*2;  // 50,890,752
static constexpr size_t XPAD_BYTES  = (size_t)B_*TP*FP*256*2;  // 16,963,584
static constexpr size_t QF_BYTES    = (size_t)B_*64*LPAD*256*2;// 16,777,216
static constexpr size_t QT_BYTES    = (size_t)B_*T_*64*256*2;  // 16,318,464
static constexpr size_t WT_BYTES    = (size_t)9*1536*256*2;    //  7,077,888
static constexpr size_t WFT_BYTES   = (size_t)9*64*768*2;      //    884,736

static constexpr size_t OFF_FUSED = 0;
static constexpr size_t OFF_XPAD  = OFF_FUSED + FUSED_BYTES;
static constexpr size_t OFF_QF    = OFF_XPAD  + XPAD_BYTES;
static constexpr size_t OFF_KF    = OFF_QF + QF_BYTES;
static constexpr size_t OFF_VF    = OFF_KF + QF_BYTES;
static constexpr size_t OFF_QT    = OFF_VF + QF_BYTES;
static constexpr size_t OFF_KT    = OFF_QT + QT_BYTES;
static constexpr size_t OFF_VT    = OFF_KT + QT_BYTES;
static constexpr size_t OFF_WT    = OFF_VT + QT_BYTES;
static constexpr size_t OFF_WFT   = OFF_WT + WT_BYTES;
static constexpr size_t OFF_BALL  = OFF_WFT + WFT_BYTES;
static constexpr size_t OFF_BF    = OFF_BALL + 1536*4;
static constexpr size_t WS_NEED   = OFF_BF + 64*4;   // ~167 MiB

__device__ __forceinline__ f32x4 mfma16(f16x8 a, f16x8 b, f32x4 c) {
    return __builtin_amdgcn_mfma_f32_16x16x32_f16(a, b, c, 0, 0, 0);
}

// global -> LDS direct copy, 16B per lane. LDS dest must be wave-uniform
// (HW adds lane*16); global src is per-lane.
__device__ __forceinline__ void gl_lds16(const void* g, void* l) {
    __builtin_amdgcn_global_load_lds(
        (const __attribute__((address_space(1))) unsigned int*)(unsigned long long)g,
        (__attribute__((address_space(3))) unsigned int*)(unsigned int)(unsigned long long)l,
        16, 0, 0);
}

// ---------------------------------------------------------------------------
// prep_wT: transpose the six QKV conv weights into wT[tap][n(1536)][c(256)]
// fp16 via LDS (both global sides coalesced). 216 blocks = 9 taps x 6
// tensors x 4 c-chunks. Tap indices swapped for _f (AFAB) weights.
// ---------------------------------------------------------------------------
__global__ __launch_bounds__(256) void prep_wT(
    const float* __restrict__ wqf, const float* __restrict__ wkf, const float* __restrict__ wvf,
    const float* __restrict__ wqt, const float* __restrict__ wkt, const float* __restrict__ wvt,
    f16* __restrict__ wT)
{
    __shared__ float lt[64][257];
    const int bid = blockIdx.x;            // 0..215
    const int tap = bid / 24;
    const int rr  = bid - tap*24;
    const int blk = rr >> 2, cq = rr & 3;
    const int dt = tap/3 - 1, df = tap%3 - 1;
    const float* w; int kh, kw;
    if (blk < 3) { w = (blk==0) ? wqf : (blk==1) ? wkf : wvf; kh = df+1; kw = dt+1; }
    else         { w = (blk==3) ? wqt : (blk==4) ? wkt : wvt; kh = dt+1; kw = df+1; }
    const int c0 = cq*64;
    const int tid = threadIdx.x;

    const float* src = w + ((size_t)(kh*3 + kw)*256 + c0)*256 + tid;
    for (int cr = 0; cr < 64; ++cr)
        lt[cr][tid] = src[(size_t)cr*256];
    __syncthreads();

    const int cc = tid & 63, ng = tid >> 6;
    f16* dst = wT + ((size_t)tap*1536 + blk*256)*256 + c0 + cc;
    for (int j = 0; j < 64; ++j) {
        int n = j*4 + ng;
        dst[(size_t)n*256] = (f16)lt[cc][n];
    }
}

// ---------------------------------------------------------------------------
// prep_wmisc: w_final -> wfT[tap][oc(64)][cin(768)], plus bias packs.
// ---------------------------------------------------------------------------
__global__ __launch_bounds__(256) void prep_wmisc(
    const float* __restrict__ wfin,
    const float* __restrict__ bqf, const float* __restrict__ bkf, const float* __restrict__ bvf,
    const float* __restrict__ bqt, const float* __restrict__ bkt, const float* __restrict__ bvt,
    const float* __restrict__ bfin,
    f16* __restrict__ wfT, float* __restrict__ biasAll, float* __restrict__ biasF)
{
    int idx = blockIdx.x*256 + threadIdx.x;
    if (idx < 9*64*768) {
        int tap = idx / (64*768);
        int r   = idx - tap*(64*768);
        int oc = r / 768, cin = r - oc*768;
        int dt = tap/3 - 1, df = tap%3 - 1;
        wfT[idx] = (f16)wfin[(((dt+1)*3 + (df+1))*768 + cin)*64 + oc];
    }
    if (idx < 1536) {
        int blk = idx >> 8, nl = idx & 255;
        const float* bb = (blk==0)?bqf:(blk==1)?bkf:(blk==2)?bvf:(blk==3)?bqt:(blk==4)?bkt:bvt;
        biasAll[idx] = bb[nl];
    }
    if (idx < 64) biasF[idx] = bfin[idx];
}

// ---------------------------------------------------------------------------
// prep_x: x (f32) -> xpad (padded fp16) and fused[...][512..767].
// ---------------------------------------------------------------------------
__global__ __launch_bounds__(256) void prep_x(
    const float* __restrict__ x, f16* __restrict__ xpad, f16* __restrict__ fused)
{
    int tid = blockIdx.x*256 + threadIdx.x;     // NPIX*32 exact
    int pix = tid >> 5, c8 = (tid & 31)*8;
    int b = pix / PIXB; int r = pix - b*PIXB;
    int t = r >> 6, f = r & 63;
    const float* src = x + (size_t)pix*256 + c8;
    f16x8 v;
#pragma unroll
    for (int j = 0; j < 8; ++j) v[j] = (f16)src[j];
    size_t pp = (size_t)(b*TP + t + 1)*FP + (f + 1);
    *(f16x8*)(xpad + pp*256 + c8) = v;
    *(f16x8*)(fused + pp*768 + 512 + c8) = v;
}

// ---------------------------------------------------------------------------
// border_zero: zero only the padded-border pixels of xpad (256ch) and fused
// (768ch). 630 border pixels per batch.
// ---------------------------------------------------------------------------
__global__ __launch_bounds__(256) void border_zero(
    f16* __restrict__ xpad, f16* __restrict__ fused)
{
    int pix = blockIdx.x*2 + (threadIdx.x >> 7);   // 0..1259
    int tl = threadIdx.x & 127;
    int b = pix / 630; int i = pix - b*630;
    int tp, fp;
    if (i < 66)       { tp = 0;   fp = i; }
    else if (i < 132) { tp = 250; fp = i - 66; }
    else { int j = i - 132; tp = 1 + (j >> 1); fp = (j & 1) * 65; }
    size_t pp = (size_t)(b*TP + tp)*FP + fp;
    f16x8 z = {0, 0, 0, 0, 0, 0, 0, 0};
    if (tl < 32) *(f16x8*)(xpad + pp*256 + tl*8) = z;
    if (tl < 96) *(f16x8*)(fused + pp*768 + tl*8) = z;
}

// ---------------------------------------------------------------------------
// vf_pad: zero only vf's pad columns (t in [249,256)) -- PV multiplies them
// by P=0, so they must be finite. Replaces a 16.7MB memset.
// ---------------------------------------------------------------------------
__global__ __launch_bounds__(256) void vf_pad(f16* __restrict__ vf)
{
    int head = blockIdx.x;                // 0..127
    int c = threadIdx.x;                  // 0..255
    f16* p = vf + ((size_t)head*256 + c)*LPAD;
#pragma unroll
    for (int t = T_; t < LPAD; ++t) p[t] = (f16)0.f;
}

// ---------------------------------------------------------------------------
// conv_qkv: m201-faithful phase-interleaved pipeline.
//   M = 126 tiles x 256 pixels (63/batch; last tile 1 valid trow, clamped
//   loads + guarded stores, r6-proven). N = 6 tiles x 256 (one tensor each).
//   K = 36 tiles of 64 (9 taps x 4 ch-chunks), split into k-halves of 32.
//   512 thr = 8 waves (2M x 4N), wave tile 128x64, acc 8x4 f32x4.
//   LDS: A dbuf x 2 half [256][32] f16 (16KB/sub) + B same = 128 KB.
//   Sub-buffer slot (row,oct) holds global k-octet (oct ^ (row&3)) -- frag
//   reads become a permutation of a contiguous 1KB block (<=2-way, free).
//   Per K-tile, 4 phases (s-half of M x kk-half of K), each:
//     {ds_read 4 A-frags (+4 B-frags at s0) ; stage ONE half-tile (2 gl_lds)
//      ; barrier ; lgkmcnt(0) ; 16 MFMA (setprio) ; [vmcnt(4) at P2/P4]
//      ; barrier}
//   FIFO proof: at each vmcnt(4), exactly the two half-tiles needed next
//   have retired; the two staged later stay in flight. Never 0 until kt=35.
// ---------------------------------------------------------------------------
__global__ __launch_bounds__(512) void conv_qkv(
    const f16* __restrict__ xpad, const f16* __restrict__ wT,
    const float* __restrict__ biasAll,
    f16* __restrict__ qf, f16* __restrict__ kf, f16* __restrict__ vf,
    f16* __restrict__ qt, f16* __restrict__ kt_, f16* __restrict__ vt)
{
    __shared__ f16 smemA[2*2*8192];   // [db][h][256][32] = 64 KB
    __shared__ f16 smemB[2*2*8192];   // 64 KB

    // XCD-local decode: 126 mt tiles partitioned per XCD, nt-outer.
    const int xcd = blockIdx.x & 7, lin = blockIdx.x >> 3;
    const int mtcnt = (xcd < 6) ? 16 : 15;       // 6*16 + 2*15 = 126
    if (lin >= 6*mtcnt) return;
    const int mtbase = (xcd < 6) ? xcd*16 : 96 + (xcd - 6)*15;
    const int nt = lin / mtcnt;
    const int mt = mtbase + (lin - nt*mtcnt);    // 0..125

    const int bb = mt / 63;
    const int tloc = mt - bb*63;                 // tile within batch

    const int tid = threadIdx.x;
    const int l   = tid & 63;
    const int wid = tid >> 6;
    const int wm = wid >> 2, wn = wid & 3;       // 2M x 4N
    const int g  = l >> 4;                        // k-octet 0..3

    // --- staging sources (f16 elem offsets); oct pre-swizzled on source ---
    int aS[2], bS[2];
#pragma unroll
    for (int u = 0; u < 2; ++u) {
        int idx = u*512 + tid;                   // 0..1023
        int r = idx >> 2, oct = idx & 3;
        int go = oct ^ (r & 3);
        int pib = tloc*256 + r; if (pib > PIXB-1) pib = PIXB-1;
        int t = pib >> 6, f = pib & 63;
        aS[u] = ((bb*TP + t + 1)*FP + (f + 1))*256 + go*8;
        bS[u] = (nt*256 + r)*256 + go*8;
    }

    // --- fragment row offsets (f16 units) + oct-swizzle keys ---
    int lrA[8], kA[8];
#pragma unroll
    for (int m = 0; m < 8; ++m) {
        int lr = wm*128 + m*16 + (l & 15);
        lrA[m] = lr*32; kA[m] = lr & 3;
    }
    int lrB[4], kB[4];
#pragma unroll
    for (int n = 0; n < 4; ++n) {
        int lr = wn*64 + n*16 + (l & 15);
        lrB[n] = lr*32; kB[n] = lr & 3;
    }

    f32x4 acc[8][4];
#pragma unroll
    for (int m = 0; m < 8; ++m)
#pragma unroll
        for (int n = 0; n < 4; ++n) acc[m][n] = {0.f, 0.f, 0.f, 0.f};

#define SB   __builtin_amdgcn_sched_barrier(0)
#define BARR __builtin_amdgcn_s_barrier()
#define LGKM asm volatile("s_waitcnt lgkmcnt(0)" ::: "memory")
#define VM4  asm volatile("s_waitcnt vmcnt(4)" ::: "memory")
#define VM0  asm volatile("s_waitcnt vmcnt(0)" ::: "memory")
#define RDA(S, BASE) do {                                                      \
        _Pragma("unroll")                                                      \
        for (int m_ = 0; m_ < 4; ++m_)                                         \
            af[m_] = *(const f16x8*)((BASE) + lrA[(S)*4 + m_]                  \
                                     + ((g ^ kA[(S)*4 + m_]) << 3));           \
    } while (0)
#define RDB(BASE) do {                                                         \
        _Pragma("unroll")                                                      \
        for (int n_ = 0; n_ < 4; ++n_)                                         \
            bf[n_] = *(const f16x8*)((BASE) + lrB[n_]                          \
                                     + ((g ^ kB[n_]) << 3));                   \
    } while (0)
#define MM(S) do {                                                             \
        __builtin_amdgcn_s_setprio(1);                                         \
        _Pragma("unroll")                                                      \
        for (int m_ = 0; m_ < 4; ++m_)                                         \
            _Pragma("unroll")                                                  \
            for (int n_ = 0; n_ < 4; ++n_)                                     \
                acc[(S)*4 + m_][n_] = mfma16(af[m_], bf[n_], acc[(S)*4 + m_][n_]); \
        __builtin_amdgcn_s_setprio(0);                                         \
    } while (0)
#define GA(DST, U, HOFF) \
        gl_lds16(xpad + aS[U] + ashn + (HOFF), (DST) + ((U)*512 + wid*64)*8)
#define GB(DST, U, HOFF) \
        gl_lds16(wT + bS[U] + bshn + (HOFF), (DST) + ((U)*512 + wid*64)*8)

    // --- prologue: stage tile 0 (A h0, B h0, A h1, B h1) into db=0 ---
    {
        const int ashn = (-1*FP - 1)*256;        // tap0 (dt=df=-1), kc0
        const size_t bshn = 0;
        GA(smemA + 0*8192, 0, 0);  GA(smemA + 0*8192, 1, 0);
        GB(smemB + 0*8192, 0, 0);  GB(smemB + 0*8192, 1, 0);
        GA(smemA + 1*8192, 0, 32); GA(smemA + 1*8192, 1, 32);
        GB(smemB + 1*8192, 0, 32); GB(smemB + 1*8192, 1, 32);
        SB; VM4; BARR; SB;                       // A0h0,B0h0 landed
    }

#pragma unroll 1
    for (int kt = 0; kt < 36; ++kt) {
        const int db = kt & 1;
        const f16* Ac0 = smemA + (db*2 + 0)*8192;
        const f16* Ac1 = smemA + (db*2 + 1)*8192;
        const f16* Bc0 = smemB + (db*2 + 0)*8192;
        const f16* Bc1 = smemB + (db*2 + 1)*8192;
        f16* An0 = smemA + ((db^1)*2 + 0)*8192;
        f16* An1 = smemA + ((db^1)*2 + 1)*8192;
        f16* Bn0 = smemB + ((db^1)*2 + 0)*8192;
        f16* Bn1 = smemB + ((db^1)*2 + 1)*8192;
        const int ktn = kt + 1;
        const bool st = ktn < 36;
        const int tapn = ktn >> 2, kcn = ktn & 3;
        const int ashn = st ? ((tapn/3 - 1)*FP + (tapn%3 - 1))*256 + kcn*64 : 0;
        const size_t bshn = st ? (size_t)tapn*(1536*256) + kcn*64 : 0;

        f16x8 af[4], bf[4];

        // P1: (s0,k0); stage A'(h0)
        RDB(Bc0); RDA(0, Ac0);
        if (st) { GA(An0, 0, 0); GA(An0, 1, 0); }
        SB; BARR; LGKM; SB;
        MM(0);
        SB; BARR;

        // P2: (s1,k0); stage B'(h0); counted wait for (kt)'s h1 halves
        RDA(1, Ac0);
        if (st) { GB(Bn0, 0, 0); GB(Bn0, 1, 0); }
        SB; BARR; LGKM; SB;
        MM(1);
        SB;
        if (kt < 35) VM4; else VM0;
        BARR;

        // P3: (s0,k1); stage A'(h1)
        RDB(Bc1); RDA(0, Ac1);
        if (st) { GA(An1, 0, 32); GA(An1, 1, 32); }
        SB; BARR; LGKM; SB;
        MM(0);
        SB; BARR;

        // P4: (s1,k1); stage B'(h1); counted wait for (kt+1)'s h0 halves
        RDA(1, Ac1);
        if (st) { GB(Bn1, 0, 32); GB(Bn1, 1, 32); }
        SB; BARR; LGKM; SB;
        MM(1);
        SB;
        if (kt < 35) VM4; else VM0;
        BARR;
    }
#undef SB
#undef BARR
#undef LGKM
#undef VM4
#undef VM0
#undef RDA
#undef RDB
#undef MM
#undef GA
#undef GB

    // --- epilogue: scatter into attention-friendly layouts ---
    f16* dst = (nt==0)?qf:(nt==1)?kf:(nt==2)?vf:(nt==3)?qt:(nt==4)?kt_:vt;
#pragma unroll
    for (int m = 0; m < 8; ++m) {
#pragma unroll
        for (int rg = 0; rg < 4; ++rg) {
            int row = wm*128 + m*16 + (l >> 4)*4 + rg;   // D: row=(l>>4)*4+reg
            int pib = tloc*256 + row;
            int t = pib >> 6, f = pib & 63;
            if (t <= 248) {
#pragma unroll
                for (int n = 0; n < 4; ++n) {
                    int col = wn*64 + n*16 + (l & 15);   // D: col=l&15
                    float v = acc[m][n][rg] + biasAll[nt*256 + col];
                    int off;
                    if (nt < 2)       off = ((bb*64 + f)*LPAD + t)*256 + col;
                    else if (nt == 2) off = ((bb*64 + f)*256 + col)*LPAD + t;
                    else if (nt < 5)  off = ((bb*T_ + t)*64 + f)*256 + col;
                    else              off = ((bb*T_ + t)*256 + col)*64 + f;
                    dst[off] = (f16)v;
                }
            }
        }
    }
}

// ---------------------------------------------------------------------------
// attn_f: heads (b,f), attention over T (249, padded to 256). (r7)
// ---------------------------------------------------------------------------
__global__ __launch_bounds__(256) void attn_f(
    const f16* __restrict__ qf, const f16* __restrict__ kf, const f16* __restrict__ vf,
    const float* __restrict__ alpha, f16* __restrict__ fused)
{
    __shared__ f16 plds[4][16*256];  // wave-private P strips
    const int l = threadIdx.x & 63;
    const int wid = threadIdx.x >> 6;
    const int head = blockIdx.x >> 2;
    const int qb = blockIdx.x & 3;
    const int b = head >> 6, f = head & 63;
    const f16* qh = qf + (size_t)head*LPAD*256;
    const f16* kh = kf + (size_t)head*LPAD*256;
    const f16* vh = vf + (size_t)head*256*LPAD;
    const int qr0 = qb*64 + wid*16;
    f16* pw = &plds[wid][0];

    f16x8 qa[8];
#pragma unroll
    for (int ks = 0; ks < 8; ++ks)
        qa[ks] = *(const f16x8*)(qh + (qr0 + (l & 15))*256 + ks*32 + (l >> 4)*8);

    f32x4 s[16];
#pragma unroll
    for (int nf = 0; nf < 16; ++nf) s[nf] = {0.f, 0.f, 0.f, 0.f};
#pragma unroll
    for (int ks = 0; ks < 8; ++ks)
#pragma unroll
        for (int nf = 0; nf < 16; ++nf) {
            f16x8 bf = *(const f16x8*)(kh + (nf*16 + (l & 15))*256 + ks*32 + (l >> 4)*8);
            s[nf] = mfma16(qa[ks], bf, s[nf]);
        }

    float inv[4];
#pragma unroll
    for (int rg = 0; rg < 4; ++rg) {
        float m = -1e30f;
#pragma unroll
        for (int nf = 0; nf < 16; ++nf)
            if (nf*16 + (l & 15) < T_) m = fmaxf(m, s[nf][rg]);
#pragma unroll
        for (int d = 1; d < 16; d <<= 1) m = fmaxf(m, __shfl_xor(m, d, 64));
        float sum = 0.f;
#pragma unroll
        for (int nf = 0; nf < 16; ++nf) {
            float p = (nf*16 + (l & 15) < T_) ? __expf(s[nf][rg] - m) : 0.f;
            s[nf][rg] = p;   // unnormalized P; 1/sum folded into epilogue
            sum += p;
        }
#pragma unroll
        for (int d = 1; d < 16; d <<= 1) sum += __shfl_xor(sum, d, 64);
        inv[rg] = 1.f / sum;
    }

#pragma unroll
    for (int nf = 0; nf < 16; ++nf)
#pragma unroll
        for (int rg = 0; rg < 4; ++rg) {
            int row = (l >> 4)*4 + rg;
            int col = nf*16 + (l & 15);
            int byte = (row*512 + col*2) ^ ((row & 7) << 4);
            *(f16*)((char*)pw + byte) = (f16)s[nf][rg];
        }

    f32x4 o[16];
#pragma unroll
    for (int nf = 0; nf < 16; ++nf) o[nf] = {0.f, 0.f, 0.f, 0.f};
#pragma unroll
    for (int ks = 0; ks < 8; ++ks) {
        int row = l & 15;
        int cch = ks*4 + (l >> 4);
        int byte = row*512 + ((cch ^ (row & 7)) << 4);
        f16x8 pa = *(const f16x8*)((const char*)pw + byte);
#pragma unroll
        for (int nf = 0; nf < 16; ++nf) {
            f16x8 bf = *(const f16x8*)(vh + (nf*16 + (l & 15))*LPAD + ks*32 + (l >> 4)*8);
            o[nf] = mfma16(pa, bf, o[nf]);
        }
    }

#pragma unroll
    for (int rg = 0; rg < 4; ++rg) {
        int t = qr0 + (l >> 4)*4 + rg;
        if (t < T_) {
#pragma unroll
            for (int nf = 0; nf < 16; ++nf) {
                int c = nf*16 + (l & 15);
                float v = o[nf][rg] * inv[rg] * alpha[((size_t)(b*T_ + t)*64 + f)*256 + c];
                fused[((size_t)(b*TP + t + 1)*FP + (f + 1))*768 + c] = (f16)v;
            }
        }
    }
}

// ---------------------------------------------------------------------------
// attn_t: heads (b,t), attention over F (64, exact). (r7)
// ---------------------------------------------------------------------------
__global__ __launch_bounds__(256) void attn_t(
    const f16* __restrict__ qt, const f16* __restrict__ kt, const f16* __restrict__ vt,
    const float* __restrict__ beta, f16* __restrict__ fused)
{
    __shared__ f16 plds[4][16*64];
    const int l = threadIdx.x & 63;
    const int wid = threadIdx.x >> 6;
    const int head = blockIdx.x;        // b*249 + t
    const int b = head / T_, t = head - b*T_;
    const f16* qh = qt + (size_t)head*64*256;
    const f16* kh = kt + (size_t)head*64*256;
    const f16* vh = vt + (size_t)head*256*64;
    const int qr0 = wid*16;
    f16* pw = &plds[wid][0];

    f16x8 qa[8];
#pragma unroll
    for (int ks = 0; ks < 8; ++ks)
        qa[ks] = *(const f16x8*)(qh + (qr0 + (l & 15))*256 + ks*32 + (l >> 4)*8);

    f32x4 s[4];
#pragma unroll
    for (int nf = 0; nf < 4; ++nf) s[nf] = {0.f, 0.f, 0.f, 0.f};
#pragma unroll
    for (int ks = 0; ks < 8; ++ks)
#pragma unroll
        for (int nf = 0; nf < 4; ++nf) {
            f16x8 bf = *(const f16x8*)(kh + (nf*16 + (l & 15))*256 + ks*32 + (l >> 4)*8);
            s[nf] = mfma16(qa[ks], bf, s[nf]);
        }

    float inv[4];
#pragma unroll
    for (int rg = 0; rg < 4; ++rg) {
        float m = -1e30f;
#pragma unroll
        for (int nf = 0; nf < 4; ++nf) m = fmaxf(m, s[nf][rg]);
#pragma unroll
        for (int d = 1; d < 16; d <<= 1) m = fmaxf(m, __shfl_xor(m, d, 64));
        float sum = 0.f;
#pragma unroll
        for (int nf = 0; nf < 4; ++nf) {
            float p = __expf(s[nf][rg] - m);
            s[nf][rg] = p;
            sum += p;
        }
#pragma unroll
        for (int d = 1; d < 16; d <<= 1) sum += __shfl_xor(sum, d, 64);
        inv[rg] = 1.f / sum;
    }

#pragma unroll
    for (int nf = 0; nf < 4; ++nf)
#pragma unroll
        for (int rg = 0; rg < 4; ++rg) {
            int row = (l >> 4)*4 + rg;
            int col = nf*16 + (l & 15);
            int byte = (row*128 + col*2) ^ ((row & 7) << 4);
            *(f16*)((char*)pw + byte) = (f16)s[nf][rg];
        }

    f32x4 o[16];
#pragma unroll
    for (int nf = 0; nf < 16; ++nf) o[nf] = {0.f, 0.f, 0.f, 0.f};
#pragma unroll
    for (int ks = 0; ks < 2; ++ks) {
        int row = l & 15;
        int cch = ks*4 + (l >> 4);
        int byte = row*128 + ((cch ^ (row & 7)) << 4);
        f16x8 pa = *(const f16x8*)((const char*)pw + byte);
#pragma unroll
        for (int nf = 0; nf < 16; ++nf) {
            f16x8 bf = *(const f16x8*)(vh + (nf*16 + (l & 15))*64 + ks*32 + (l >> 4)*8);
            o[nf] = mfma16(pa, bf, o[nf]);
        }
    }

#pragma unroll
    for (int rg = 0; rg < 4; ++rg) {
        int fo = qr0 + (l >> 4)*4 + rg;
#pragma unroll
        for (int nf = 0; nf < 16; ++nf) {
            int c = nf*16 + (l & 15);
            float v = o[nf][rg] * inv[rg] * beta[((size_t)(b*T_ + t)*64 + fo)*256 + c];
            fused[((size_t)(b*TP + t + 1)*FP + (fo + 1))*768 + 256 + c] = (f16)v;
        }
    }
}

// ---------------------------------------------------------------------------
// conv_final: implicit GEMM with fused-halo reuse (r7, unchanged).
// ---------------------------------------------------------------------------
__global__ __launch_bounds__(256, 2) void conv_final(
    const f16* __restrict__ fused, const f16* __restrict__ wfT,
    const float* __restrict__ biasF, float* __restrict__ out)
{
    __shared__ f16 smemH[288*64];     // 36 KB halo
    __shared__ f16 smemB[2][64*64];   // 16 KB B double-buffer

    const int mt = blockIdx.x;        // 0..249
    const int bb = mt / 125;
    const int t0 = (mt - bb*125) * 2; // 0..248
    const int Gs66 = (bb*TP + t0) * 66;

    const int tid = threadIdx.x;
    const int l   = tid & 63;
    const int wid = tid >> 6;
    const int wm = wid >> 1, wn = wid & 1;

    int hOff[9];
#pragma unroll
    for (int j = 0; j < 9; ++j) {
        int ps = j*32 + (tid >> 3);
        if (ps > 263) ps = 263;
        { int pm = XPOS - 1 - (bb*TP + t0)*66; if (ps > pm) ps = pm; }
        int ch = (tid & 7) ^ (ps & 7);
        hOff[j] = (Gs66 + ps)*768 + ch*8;
    }
    int bSrc[2];
#pragma unroll
    for (int j = 0; j < 2; ++j) {
        int row = j*32 + (tid >> 3);
        int ch  = (tid & 7) ^ (row & 7);
        bSrc[j] = row*768 + ch*8;
    }

    int pos00[4];
#pragma unroll
    for (int m = 0; m < 4; ++m) {
        int r = wm*64 + m*16 + (l & 15);      // 0..127
        pos00[m] = ((r >> 6) + 1)*66 + (r & 63) + 1;
    }
    int bRow[2], bSw[2];
#pragma unroll
    for (int n = 0; n < 2; ++n) {
        int row = wn*32 + n*16 + (l & 15);
        bRow[n] = row*64; bSw[n] = row & 7;
    }

    f32x4 acc[4][2];
#pragma unroll
    for (int m = 0; m < 4; ++m)
#pragma unroll
        for (int n = 0; n < 2; ++n) acc[m][n] = {0.f, 0.f, 0.f, 0.f};

#define FHSTAGE(C) do {                                                        \
        _Pragma("unroll")                                                      \
        for (int j_ = 0; j_ < 9; ++j_)                                         \
            gl_lds16(fused + hOff[j_] + (C)*64,                                \
                     smemH + (j_*256 + wid*64)*8);                             \
    } while (0)

#define FBSTAGE(TAP, C, NB) do {                                               \
        const f16* wt_ = wfT + (size_t)(TAP)*(64*768) + (C)*64;                \
        _Pragma("unroll")                                                      \
        for (int j_ = 0; j_ < 2; ++j_)                                         \
            gl_lds16(wt_ + bSrc[j_], &smemB[NB][(j_*256 + wid*64)*8]);         \
    } while (0)

#define FCOMP(NB, TAPOFF) do {                                                 \
        int pos_[4];                                                           \
        _Pragma("unroll")                                                      \
        for (int m = 0; m < 4; ++m) pos_[m] = pos00[m] + (TAPOFF);             \
        _Pragma("unroll")                                                      \
        for (int kk = 0; kk < 2; ++kk) {                                       \
            const int cch = kk*4 + (l >> 4);                                   \
            f16x8 af[4], bf[2];                                                \
            _Pragma("unroll")                                                  \
            for (int m = 0; m < 4; ++m)                                        \
                af[m] = *(const f16x8*)(smemH + pos_[m]*64 + ((cch ^ (pos_[m] & 7)) << 3)); \
            _Pragma("unroll")                                                  \
            for (int n = 0; n < 2; ++n)                                        \
                bf[n] = *(const f16x8*)(&smemB[NB][0] + bRow[n] + ((cch ^ bSw[n]) << 3)); \
            __builtin_amdgcn_s_setprio(1);                                     \
            _Pragma("unroll")                                                  \
            for (int m = 0; m < 4; ++m)                                        \
                _Pragma("unroll")                                              \
                for (int n = 0; n < 2; ++n)                                    \
                    acc[m][n] = mfma16(af[m], bf[n], acc[m][n]);               \
            __builtin_amdgcn_s_setprio(0);                                     \
        }                                                                      \
    } while (0)

    int buf = 0;
    FHSTAGE(0);
    FBSTAGE(0, 0, 0);
    __syncthreads();
    for (int c = 0; c < 12; ++c) {
        for (int tap = 0; tap < 9; ++tap) {
            if (tap < 8)       FBSTAGE(tap + 1, c, buf ^ 1);
            else if (c < 11)   FBSTAGE(0, c + 1, buf ^ 1);
            const int dt = tap/3 - 1, df = tap - (tap/3)*3 - 1;
            FCOMP(buf, dt*66 + df);
            __syncthreads();
            buf ^= 1;
        }
        if (c < 11) {
            FHSTAGE(c + 1);
            __syncthreads();
        }
    }
#undef FHSTAGE
#undef FBSTAGE
#undef FCOMP

#pragma unroll
    for (int m = 0; m < 4; ++m) {
#pragma unroll
        for (int rg = 0; rg < 4; ++rg) {
            int r = wm*64 + m*16 + (l >> 4)*4 + rg;      // D: row=(l>>4)*4+reg
            int t = t0 + (r >> 6), f = r & 63;
            if (t <= 248) {
                size_t pix = (size_t)bb*PIXB + t*64 + f;
#pragma unroll
                for (int n = 0; n < 2; ++n) {
                    int oc = wn*32 + n*16 + (l & 15);    // D: col=l&15
                    out[pix*64 + oc] = acc[m][n][rg] + biasF[oc];
                }
            }
        }
    }
}

// ---------------------------------------------------------------------------
extern "C" void kernel_launch(void* const* d_in, const int* in_sizes, int n_in,
                              void* d_out, int out_size, void* d_ws, size_t ws_size,
                              hipStream_t stream) {
    (void)in_sizes; (void)n_in; (void)out_size;
    const float* x    = (const float*)d_in[0];
    const float* wqf  = (const float*)d_in[1];
    const float* bqf  = (const float*)d_in[2];
    const float* wkf  = (const float*)d_in[3];
    const float* bkf  = (const float*)d_in[4];
    const float* wvf  = (const float*)d_in[5];
    const float* bvf  = (const float*)d_in[6];
    const float* wqt  = (const float*)d_in[7];
    const float* bqt  = (const float*)d_in[8];
    const float* wkt  = (const float*)d_in[9];
    const float* bkt  = (const float*)d_in[10];
    const float* wvt  = (const float*)d_in[11];
    const float* bvt  = (const float*)d_in[12];
    const float* wfin = (const float*)d_in[13];
    const float* bfin = (const float*)d_in[14];
    const float* alpha= (const float*)d_in[15];
    const float* beta = (const float*)d_in[16];

    if (ws_size < WS_NEED) return;   // workspace insufficient -> visible failure

    char* ws = (char*)d_ws;
    f16* fused  = (f16*)(ws + OFF_FUSED);
    f16* xpad   = (f16*)(ws + OFF_XPAD);
    f16* qf     = (f16*)(ws + OFF_QF);
    f16* kf     = (f16*)(ws + OFF_KF);
    f16* vf     = (f16*)(ws + OFF_VF);
    f16* qt     = (f16*)(ws + OFF_QT);
    f16* kt     = (f16*)(ws + OFF_KT);
    f16* vt     = (f16*)(ws + OFF_VT);
    f16* wT     = (f16*)(ws + OFF_WT);
    f16* wfT    = (f16*)(ws + OFF_WFT);
    float* bAll = (float*)(ws + OFF_BALL);
    float* bF   = (float*)(ws + OFF_BF);

    border_zero<<<dim3(630), dim3(256), 0, stream>>>(xpad, fused);
    vf_pad<<<dim3(128), dim3(256), 0, stream>>>(vf);
    prep_wT<<<dim3(216), dim3(256), 0, stream>>>(wqf, wkf, wvf, wqt, wkt, wvt, wT);
    prep_wmisc<<<dim3(1728), dim3(256), 0, stream>>>(
        wfin, bqf, bkf, bvf, bqt, bkt, bvt, bfin, wfT, bAll, bF);
    prep_x<<<dim3(NPIX*32/256), dim3(256), 0, stream>>>(x, xpad, fused);
    conv_qkv<<<dim3(768), dim3(512), 0, stream>>>(xpad, wT, bAll, qf, kf, vf, qt, kt, vt);
    attn_f<<<dim3(512), dim3(256), 0, stream>>>(qf, kf, vf, alpha, fused);
    attn_t<<<dim3(498), dim3(256), 0, stream>>>(qt, kt, vt, beta, fused);
    conv_final<<<dim3(250), dim3(256), 0, stream>>>(fused, wfT, bF, (float*)d_out);
}

// Round 10
// 472.998 us; speedup vs baseline: 1.0885x; 1.0885x over previous
//
#include <hip/hip_runtime.h>

// ---------------------------------------------------------------------------
// ATFA: dual-axis conv-attention, MI355X fp16-MFMA implementation.
// Round 10: best-known composition. conv_qkv = round-8 4-phase counted-vmcnt
// pipeline (285us, 0 bank conflicts; r9's [256][32] layout caused 2e7
// conflicts and is reverted). prep = r9 (LDS-transposed prep_wT, targeted
// vf_pad). conv_final = r7 halo. attn = unchanged.
// ---------------------------------------------------------------------------

typedef _Float16 f16;
typedef _Float16 f16x8 __attribute__((ext_vector_type(8)));
typedef float    f32x4 __attribute__((ext_vector_type(4)));

#define B_   2
#define T_   249
#define F_   64
#define TP   251     // T + 2 (padded)
#define FP   66      // F + 2 (padded)
#define PIXB (T_*F_) // 15936 pixels per batch
#define NPIX (B_*PIXB)
#define LPAD 256     // padded attention length for the T-axis heads
#define XPOS (B_*TP*FP)   // 33132 padded positions

static constexpr size_t FUSED_BYTES = (size_t)B_*TP*FP*768*2;  // 50,890,752
static constexpr size_t XPAD_BYTES  = (size_t)B_*TP*FP*256*2;  // 16,963,584
static constexpr size_t QF_BYTES    = (size_t)B_*64*LPAD*256*2;// 16,777,216
static constexpr size_t QT_BYTES    = (size_t)B_*T_*64*256*2;  // 16,318,464
static constexpr size_t WT_BYTES    = (size_t)9*1536*256*2;    //  7,077,888
static constexpr size_t WFT_BYTES   = (size_t)9*64*768*2;      //    884,736

static constexpr size_t OFF_FUSED = 0;
static constexpr size_t OFF_XPAD  = OFF_FUSED + FUSED_BYTES;
static constexpr size_t OFF_QF    = OFF_XPAD  + XPAD_BYTES;
static constexpr size_t OFF_KF    = OFF_QF + QF_BYTES;
static constexpr size_t OFF_VF    = OFF_KF + QF_BYTES;
static constexpr size_t OFF_QT    = OFF_VF + QF_BYTES;
static constexpr size_t OFF_KT    = OFF_QT + QT_BYTES;
static constexpr size_t OFF_VT    = OFF_KT + QT_BYTES;
static constexpr size_t OFF_WT    = OFF_VT + QT_BYTES;
static constexpr size_t OFF_WFT   = OFF_WT + WT_BYTES;
static constexpr size_t OFF_BALL  = OFF_WFT + WFT_BYTES;
static constexpr size_t OFF_BF    = OFF_BALL + 1536*4;
static constexpr size_t WS_NEED   = OFF_BF + 64*4;   // ~167 MiB

__device__ __forceinline__ f32x4 mfma16(f16x8 a, f16x8 b, f32x4 c) {
    return __builtin_amdgcn_mfma_f32_16x16x32_f16(a, b, c, 0, 0, 0);
}

// global -> LDS direct copy, 16B per lane. LDS dest must be wave-uniform
// (HW adds lane*16); global src is per-lane.
__device__ __forceinline__ void gl_lds16(const void* g, void* l) {
    __builtin_amdgcn_global_load_lds(
        (const __attribute__((address_space(1))) unsigned int*)(unsigned long long)g,
        (__attribute__((address_space(3))) unsigned int*)(unsigned int)(unsigned long long)l,
        16, 0, 0);
}

// ---------------------------------------------------------------------------
// prep_wT: transpose the six QKV conv weights into wT[tap][n(1536)][c(256)]
// fp16 via LDS (both global sides coalesced). 216 blocks = 9 taps x 6
// tensors x 4 c-chunks. Tap indices swapped for _f (AFAB) weights.
// ---------------------------------------------------------------------------
__global__ __launch_bounds__(256) void prep_wT(
    const float* __restrict__ wqf, const float* __restrict__ wkf, const float* __restrict__ wvf,
    const float* __restrict__ wqt, const float* __restrict__ wkt, const float* __restrict__ wvt,
    f16* __restrict__ wT)
{
    __shared__ float lt[64][257];
    const int bid = blockIdx.x;            // 0..215
    const int tap = bid / 24;
    const int rr  = bid - tap*24;
    const int blk = rr >> 2, cq = rr & 3;
    const int dt = tap/3 - 1, df = tap%3 - 1;
    const float* w; int kh, kw;
    if (blk < 3) { w = (blk==0) ? wqf : (blk==1) ? wkf : wvf; kh = df+1; kw = dt+1; }
    else         { w = (blk==3) ? wqt : (blk==4) ? wkt : wvt; kh = dt+1; kw = df+1; }
    const int c0 = cq*64;
    const int tid = threadIdx.x;

    const float* src = w + ((size_t)(kh*3 + kw)*256 + c0)*256 + tid;
    for (int cr = 0; cr < 64; ++cr)
        lt[cr][tid] = src[(size_t)cr*256];
    __syncthreads();

    const int cc = tid & 63, ng = tid >> 6;
    f16* dst = wT + ((size_t)tap*1536 + blk*256)*256 + c0 + cc;
    for (int j = 0; j < 64; ++j) {
        int n = j*4 + ng;
        dst[(size_t)n*256] = (f16)lt[cc][n];
    }
}

// ---------------------------------------------------------------------------
// prep_wmisc: w_final -> wfT[tap][oc(64)][cin(768)], plus bias packs.
// ---------------------------------------------------------------------------
__global__ __launch_bounds__(256) void prep_wmisc(
    const float* __restrict__ wfin,
    const float* __restrict__ bqf, const float* __restrict__ bkf, const float* __restrict__ bvf,
    const float* __restrict__ bqt, const float* __restrict__ bkt, const float* __restrict__ bvt,
    const float* __restrict__ bfin,
    f16* __restrict__ wfT, float* __restrict__ biasAll, float* __restrict__ biasF)
{
    int idx = blockIdx.x*256 + threadIdx.x;
    if (idx < 9*64*768) {
        int tap = idx / (64*768);
        int r   = idx - tap*(64*768);
        int oc = r / 768, cin = r - oc*768;
        int dt = tap/3 - 1, df = tap%3 - 1;
        wfT[idx] = (f16)wfin[(((dt+1)*3 + (df+1))*768 + cin)*64 + oc];
    }
    if (idx < 1536) {
        int blk = idx >> 8, nl = idx & 255;
        const float* bb = (blk==0)?bqf:(blk==1)?bkf:(blk==2)?bvf:(blk==3)?bqt:(blk==4)?bkt:bvt;
        biasAll[idx] = bb[nl];
    }
    if (idx < 64) biasF[idx] = bfin[idx];
}

// ---------------------------------------------------------------------------
// prep_x: x (f32) -> xpad (padded fp16) and fused[...][512..767].
// ---------------------------------------------------------------------------
__global__ __launch_bounds__(256) void prep_x(
    const float* __restrict__ x, f16* __restrict__ xpad, f16* __restrict__ fused)
{
    int tid = blockIdx.x*256 + threadIdx.x;     // NPIX*32 exact
    int pix = tid >> 5, c8 = (tid & 31)*8;
    int b = pix / PIXB; int r = pix - b*PIXB;
    int t = r >> 6, f = r & 63;
    const float* src = x + (size_t)pix*256 + c8;
    f16x8 v;
#pragma unroll
    for (int j = 0; j < 8; ++j) v[j] = (f16)src[j];
    size_t pp = (size_t)(b*TP + t + 1)*FP + (f + 1);
    *(f16x8*)(xpad + pp*256 + c8) = v;
    *(f16x8*)(fused + pp*768 + 512 + c8) = v;
}

// ---------------------------------------------------------------------------
// border_zero: zero only the padded-border pixels of xpad (256ch) and fused
// (768ch). 630 border pixels per batch.
// ---------------------------------------------------------------------------
__global__ __launch_bounds__(256) void border_zero(
    f16* __restrict__ xpad, f16* __restrict__ fused)
{
    int pix = blockIdx.x*2 + (threadIdx.x >> 7);   // 0..1259
    int tl = threadIdx.x & 127;
    int b = pix / 630; int i = pix - b*630;
    int tp, fp;
    if (i < 66)       { tp = 0;   fp = i; }
    else if (i < 132) { tp = 250; fp = i - 66; }
    else { int j = i - 132; tp = 1 + (j >> 1); fp = (j & 1) * 65; }
    size_t pp = (size_t)(b*TP + tp)*FP + fp;
    f16x8 z = {0, 0, 0, 0, 0, 0, 0, 0};
    if (tl < 32) *(f16x8*)(xpad + pp*256 + tl*8) = z;
    if (tl < 96) *(f16x8*)(fused + pp*768 + tl*8) = z;
}

// ---------------------------------------------------------------------------
// vf_pad: zero only vf's pad columns (t in [249,256)) -- PV multiplies them
// by P=0, so they must be finite. Replaces a 16.7MB memset.
// ---------------------------------------------------------------------------
__global__ __launch_bounds__(256) void vf_pad(f16* __restrict__ vf)
{
    int head = blockIdx.x;                // 0..127
    int c = threadIdx.x;                  // 0..255
    f16* p = vf + ((size_t)head*256 + c)*LPAD;
#pragma unroll
    for (int t = T_; t < LPAD; ++t) p[t] = (f16)0.f;
}

// ---------------------------------------------------------------------------
// conv_qkv: phase-interleaved counted-vmcnt implicit GEMM (round-8 version,
// best measured: 285us, MfmaUtil 35%, 0 bank conflicts).
//   M = 31872: 166 tiles of 192 pixels (3 trows, 83/batch exact -> no
//   clamps). N = 1536: 6 tiles of 256 (one output tensor/block).
//   K = 36 tiles of 64 (9 taps x 4 ch-chunks).
//   512 thr = 8 waves (2M x 4N), wave tile 96x64, acc 6x4 f32x4.
//   LDS: A ring-3 [192][64] (24KB/slot, slot kt%3) + B dbuf [256][64]
//   (32KB/slot, slot kt&1) = 136KB. Stage units = 8KB (1 gl_lds/thread).
//   Per tile 4 phases; stage B(kt+1) in P1/P2, A(kt+2) in P3/P4; vmcnt(3)
//   at the tile boundary (FIFO: waits A(kt+1)+B(kt+1), keeps A(kt+2) in
//   flight); vmcnt(0) for the last 2 tiles. [*][64] chunk-XOR swizzle
//   (ch ^= row&7) on source + ds_read: conflict-free.
// ---------------------------------------------------------------------------
__global__ __launch_bounds__(512) void conv_qkv(
    const f16* __restrict__ xpad, const f16* __restrict__ wT,
    const float* __restrict__ biasAll,
    f16* __restrict__ qf, f16* __restrict__ kf, f16* __restrict__ vf,
    f16* __restrict__ qt, f16* __restrict__ kt_, f16* __restrict__ vt)
{
    __shared__ f16 smemA[3*12288];   // 3 x [192][64] = 72 KB
    __shared__ f16 smemB[2*16384];   // 2 x [256][64] = 64 KB

    // XCD-local decode: 166 mt tiles partitioned per XCD, nt-outer.
    const int xcd = blockIdx.x & 7, lin = blockIdx.x >> 3;
    const int mtcnt = (xcd < 6) ? 21 : 20;       // 6*21 + 2*20 = 166
    if (lin >= 6*mtcnt) return;
    const int mtbase = (xcd < 6) ? xcd*21 : 126 + (xcd - 6)*20;
    int nt, mi;
    if (xcd < 6) { nt = lin / 21; mi = lin - nt*21; }
    else         { nt = lin / 20; mi = lin - nt*20; }
    const int mt = mtbase + mi;                  // 0..165

    const int bb = mt / 83;
    const int t0 = (mt - bb*83) * 3;             // 0..246 (rows t0..t0+2 valid)

    const int l   = threadIdx.x & 63;
    const int wid = threadIdx.x >> 6;
    const int wm = wid >> 2, wn = wid & 3;       // 2M x 4N

    // --- staging source bases (f16 elem offsets), swizzled chunk on src ---
    int aS[3];
#pragma unroll
    for (int u = 0; u < 3; ++u) {
        int r = u*64 + wid*8 + (l >> 3);         // 0..191
        int t = t0 + (r >> 6), f = r & 63;
        int ch = (l & 7) ^ (r & 7);
        aS[u] = ((bb*TP + t + 1)*FP + (f + 1))*256 + ch*8;
    }
    int bS[4];
#pragma unroll
    for (int u = 0; u < 4; ++u) {
        int r = u*64 + wid*8 + (l >> 3);         // 0..255
        int ch = (l & 7) ^ (r & 7);
        bS[u] = (nt*256 + r)*256 + ch*8;
    }

    // --- fragment offsets (f16 units within a slot) + swizzle keys ---
    int aOff[6], aKey[6];
#pragma unroll
    for (int m = 0; m < 6; ++m) {
        int lr = wm*96 + m*16 + (l & 15);
        aOff[m] = lr*64; aKey[m] = lr & 7;
    }
    int bOff[4], bKey[4];
#pragma unroll
    for (int n = 0; n < 4; ++n) {
        int lr = wn*64 + n*16 + (l & 15);
        bOff[n] = lr*64; bKey[n] = lr & 7;
    }

    f32x4 acc[6][4];
#pragma unroll
    for (int m = 0; m < 6; ++m)
#pragma unroll
        for (int n = 0; n < 4; ++n) acc[m][n] = {0.f, 0.f, 0.f, 0.f};

#define SB  __builtin_amdgcn_sched_barrier(0)
#define BARRIER do { SB; __builtin_amdgcn_s_barrier(); SB; } while (0)
#define READ_A(DST, S, KK, BASE) do {                                          \
        const int cch_ = (KK)*4 + (l >> 4);                                    \
        _Pragma("unroll")                                                      \
        for (int m_ = 0; m_ < 3; ++m_)                                         \
            DST[m_] = *(const f16x8*)((BASE) + aOff[(S)*3 + m_]                \
                                      + ((cch_ ^ aKey[(S)*3 + m_]) << 3));     \
    } while (0)
#define READ_B(KK, BASE) do {                                                  \
        const int cch_ = (KK)*4 + (l >> 4);                                    \
        _Pragma("unroll")                                                      \
        for (int n_ = 0; n_ < 4; ++n_)                                         \
            bf[n_] = *(const f16x8*)((BASE) + bOff[n_]                         \
                                     + ((cch_ ^ bKey[n_]) << 3));              \
    } while (0)
#define MFMA12(AF, S) do {                                                     \
        __builtin_amdgcn_s_setprio(1);                                         \
        _Pragma("unroll")                                                      \
        for (int m_ = 0; m_ < 3; ++m_)                                         \
            _Pragma("unroll")                                                  \
            for (int n_ = 0; n_ < 4; ++n_)                                     \
                acc[(S)*3 + m_][n_] = mfma16(AF[m_], bf[n_], acc[(S)*3 + m_][n_]); \
        __builtin_amdgcn_s_setprio(0);                                         \
    } while (0)

    // --- prologue: A(0), B(0), A(1); wait first two (vmcnt(3) keeps A(1)) ---
    {
        const int ash0 = ((0/3 - 1)*FP + (0%3 - 1))*256;     // tap0,kc0
#pragma unroll
        for (int u = 0; u < 3; ++u)
            gl_lds16(xpad + aS[u] + ash0, smemA + (u*64 + wid*8)*64);
#pragma unroll
        for (int u = 0; u < 4; ++u)
            gl_lds16(wT + bS[u], smemB + (u*64 + wid*8)*64);
        const int ash1 = ash0 + 64;                          // tap0,kc1
#pragma unroll
        for (int u = 0; u < 3; ++u)
            gl_lds16(xpad + aS[u] + ash1, smemA + 12288 + (u*64 + wid*8)*64);
        SB;
        asm volatile("s_waitcnt vmcnt(3)" ::: "memory");
        __builtin_amdgcn_s_barrier();
        SB;
    }

#pragma unroll 1
    for (int kt = 0; kt < 36; ++kt) {
        const int a  = kt - (kt/3)*3;                 // kt % 3
        const int aN = (kt+2) - ((kt+2)/3)*3;         // (kt+2) % 3
        const int d  = kt & 1;
        const f16* Ac = smemA + a*12288;
        const f16* Bc = smemB + d*16384;
        f16* An = smemA + aN*12288;
        f16* Bn = smemB + (d ^ 1)*16384;
        const bool doB = (kt + 1) < 36, doA = (kt + 2) < 36;
        // staged-tile params
        int ktB = kt + 1, ktA = kt + 2;
        int tapB = ktB >> 2, kcB = ktB & 3;
        size_t bshB = (size_t)tapB*(1536*256) + kcB*64;
        int tapA = ktA >> 2, kcA = ktA & 3;
        int ashA = ((tapA/3 - 1)*FP + (tapA%3 - 1))*256 + kcA*64;

        f16x8 bf[4], af0[3], af1[3];

        // phase 1: (s0, kk0); stage B(kt+1) u0,u1
        READ_B(0, Bc);
        READ_A(af0, 0, 0, Ac);
        if (doB) {
            gl_lds16(wT + bS[0] + bshB, Bn + (0*64 + wid*8)*64);
            gl_lds16(wT + bS[1] + bshB, Bn + (1*64 + wid*8)*64);
        }
        BARRIER;
        MFMA12(af0, 0);

        // phase 2: (s1, kk0); stage B(kt+1) u2,u3
        READ_A(af1, 1, 0, Ac);
        if (doB) {
            gl_lds16(wT + bS[2] + bshB, Bn + (2*64 + wid*8)*64);
            gl_lds16(wT + bS[3] + bshB, Bn + (3*64 + wid*8)*64);
        }
        BARRIER;
        MFMA12(af1, 1);

        // phase 3: (s0, kk1); stage A(kt+2) u0,u1
        READ_B(1, Bc);
        READ_A(af0, 0, 1, Ac);
        if (doA) {
            gl_lds16(xpad + aS[0] + ashA, An + (0*64 + wid*8)*64);
            gl_lds16(xpad + aS[1] + ashA, An + (1*64 + wid*8)*64);
        }
        BARRIER;
        MFMA12(af0, 0);

        // phase 4: (s1, kk1); stage A(kt+2) u2; tile-boundary counted wait
        READ_A(af1, 1, 1, Ac);
        if (doA)
            gl_lds16(xpad + aS[2] + ashA, An + (2*64 + wid*8)*64);
        SB;
        if (kt < 34) asm volatile("s_waitcnt vmcnt(3)" ::: "memory");
        else         asm volatile("s_waitcnt vmcnt(0)" ::: "memory");
        __builtin_amdgcn_s_barrier();
        SB;
        MFMA12(af1, 1);
    }
#undef SB
#undef BARRIER
#undef READ_A
#undef READ_B
#undef MFMA12

    // --- epilogue: scatter into attention-friendly layouts ---
    f16* dst = (nt==0)?qf:(nt==1)?kf:(nt==2)?vf:(nt==3)?qt:(nt==4)?kt_:vt;
#pragma unroll
    for (int m = 0; m < 6; ++m) {
#pragma unroll
        for (int rg = 0; rg < 4; ++rg) {
            int row = wm*96 + m*16 + (l >> 4)*4 + rg;   // D: row=(l>>4)*4+reg
            int t = t0 + (row >> 6), f = row & 63;      // always valid
#pragma unroll
            for (int n = 0; n < 4; ++n) {
                int col = wn*64 + n*16 + (l & 15);      // D: col=l&15
                float v = acc[m][n][rg] + biasAll[nt*256 + col];
                int off;
                if (nt < 2)       off = ((bb*64 + f)*LPAD + t)*256 + col;
                else if (nt == 2) off = ((bb*64 + f)*256 + col)*LPAD + t;
                else if (nt < 5)  off = ((bb*T_ + t)*64 + f)*256 + col;
                else              off = ((bb*T_ + t)*256 + col)*64 + f;
                dst[off] = (f16)v;
            }
        }
    }
}

// ---------------------------------------------------------------------------
// attn_f: heads (b,f), attention over T (249, padded to 256).
// ---------------------------------------------------------------------------
__global__ __launch_bounds__(256) void attn_f(
    const f16* __restrict__ qf, const f16* __restrict__ kf, const f16* __restrict__ vf,
    const float* __restrict__ alpha, f16* __restrict__ fused)
{
    __shared__ f16 plds[4][16*256];  // wave-private P strips
    const int l = threadIdx.x & 63;
    const int wid = threadIdx.x >> 6;
    const int head = blockIdx.x >> 2;
    const int qb = blockIdx.x & 3;
    const int b = head >> 6, f = head & 63;
    const f16* qh = qf + (size_t)head*LPAD*256;
    const f16* kh = kf + (size_t)head*LPAD*256;
    const f16* vh = vf + (size_t)head*256*LPAD;
    const int qr0 = qb*64 + wid*16;
    f16* pw = &plds[wid][0];

    f16x8 qa[8];
#pragma unroll
    for (int ks = 0; ks < 8; ++ks)
        qa[ks] = *(const f16x8*)(qh + (qr0 + (l & 15))*256 + ks*32 + (l >> 4)*8);

    f32x4 s[16];
#pragma unroll
    for (int nf = 0; nf < 16; ++nf) s[nf] = {0.f, 0.f, 0.f, 0.f};
#pragma unroll
    for (int ks = 0; ks < 8; ++ks)
#pragma unroll
        for (int nf = 0; nf < 16; ++nf) {
            f16x8 bf = *(const f16x8*)(kh + (nf*16 + (l & 15))*256 + ks*32 + (l >> 4)*8);
            s[nf] = mfma16(qa[ks], bf, s[nf]);
        }

    float inv[4];
#pragma unroll
    for (int rg = 0; rg < 4; ++rg) {
        float m = -1e30f;
#pragma unroll
        for (int nf = 0; nf < 16; ++nf)
            if (nf*16 + (l & 15) < T_) m = fmaxf(m, s[nf][rg]);
#pragma unroll
        for (int d = 1; d < 16; d <<= 1) m = fmaxf(m, __shfl_xor(m, d, 64));
        float sum = 0.f;
#pragma unroll
        for (int nf = 0; nf < 16; ++nf) {
            float p = (nf*16 + (l & 15) < T_) ? __expf(s[nf][rg] - m) : 0.f;
            s[nf][rg] = p;   // unnormalized P; 1/sum folded into epilogue
            sum += p;
        }
#pragma unroll
        for (int d = 1; d < 16; d <<= 1) sum += __shfl_xor(sum, d, 64);
        inv[rg] = 1.f / sum;
    }

#pragma unroll
    for (int nf = 0; nf < 16; ++nf)
#pragma unroll
        for (int rg = 0; rg < 4; ++rg) {
            int row = (l >> 4)*4 + rg;
            int col = nf*16 + (l & 15);
            int byte = (row*512 + col*2) ^ ((row & 7) << 4);
            *(f16*)((char*)pw + byte) = (f16)s[nf][rg];
        }

    f32x4 o[16];
#pragma unroll
    for (int nf = 0; nf < 16; ++nf) o[nf] = {0.f, 0.f, 0.f, 0.f};
#pragma unroll
    for (int ks = 0; ks < 8; ++ks) {
        int row = l & 15;
        int cch = ks*4 + (l >> 4);
        int byte = row*512 + ((cch ^ (row & 7)) << 4);
        f16x8 pa = *(const f16x8*)((const char*)pw + byte);
#pragma unroll
        for (int nf = 0; nf < 16; ++nf) {
            f16x8 bf = *(const f16x8*)(vh + (nf*16 + (l & 15))*LPAD + ks*32 + (l >> 4)*8);
            o[nf] = mfma16(pa, bf, o[nf]);
        }
    }

#pragma unroll
    for (int rg = 0; rg < 4; ++rg) {
        int t = qr0 + (l >> 4)*4 + rg;
        if (t < T_) {
#pragma unroll
            for (int nf = 0; nf < 16; ++nf) {
                int c = nf*16 + (l & 15);
                float v = o[nf][rg] * inv[rg] * alpha[((size_t)(b*T_ + t)*64 + f)*256 + c];
                fused[((size_t)(b*TP + t + 1)*FP + (f + 1))*768 + c] = (f16)v;
            }
        }
    }
}

// ---------------------------------------------------------------------------
// attn_t: heads (b,t), attention over F (64, exact).
// ---------------------------------------------------------------------------
__global__ __launch_bounds__(256) void attn_t(
    const f16* __restrict__ qt, const f16* __restrict__ kt, const f16* __restrict__ vt,
    const float* __restrict__ beta, f16* __restrict__ fused)
{
    __shared__ f16 plds[4][16*64];
    const int l = threadIdx.x & 63;
    const int wid = threadIdx.x >> 6;
    const int head = blockIdx.x;        // b*249 + t
    const int b = head / T_, t = head - b*T_;
    const f16* qh = qt + (size_t)head*64*256;
    const f16* kh = kt + (size_t)head*64*256;
    const f16* vh = vt + (size_t)head*256*64;
    const int qr0 = wid*16;
    f16* pw = &plds[wid][0];

    f16x8 qa[8];
#pragma unroll
    for (int ks = 0; ks < 8; ++ks)
        qa[ks] = *(const f16x8*)(qh + (qr0 + (l & 15))*256 + ks*32 + (l >> 4)*8);

    f32x4 s[4];
#pragma unroll
    for (int nf = 0; nf < 4; ++nf) s[nf] = {0.f, 0.f, 0.f, 0.f};
#pragma unroll
    for (int ks = 0; ks < 8; ++ks)
#pragma unroll
        for (int nf = 0; nf < 4; ++nf) {
            f16x8 bf = *(const f16x8*)(kh + (nf*16 + (l & 15))*256 + ks*32 + (l >> 4)*8);
            s[nf] = mfma16(qa[ks], bf, s[nf]);
        }

    float inv[4];
#pragma unroll
    for (int rg = 0; rg < 4; ++rg) {
        float m = -1e30f;
#pragma unroll
        for (int nf = 0; nf < 4; ++nf) m = fmaxf(m, s[nf][rg]);
#pragma unroll
        for (int d = 1; d < 16; d <<= 1) m = fmaxf(m, __shfl_xor(m, d, 64));
        float sum = 0.f;
#pragma unroll
        for (int nf = 0; nf < 4; ++nf) {
            float p = __expf(s[nf][rg] - m);
            s[nf][rg] = p;
            sum += p;
        }
#pragma unroll
        for (int d = 1; d < 16; d <<= 1) sum += __shfl_xor(sum, d, 64);
        inv[rg] = 1.f / sum;
    }

#pragma unroll
    for (int nf = 0; nf < 4; ++nf)
#pragma unroll
        for (int rg = 0; rg < 4; ++rg) {
            int row = (l >> 4)*4 + rg;
            int col = nf*16 + (l & 15);
            int byte = (row*128 + col*2) ^ ((row & 7) << 4);
            *(f16*)((char*)pw + byte) = (f16)s[nf][rg];
        }

    f32x4 o[16];
#pragma unroll
    for (int nf = 0; nf < 16; ++nf) o[nf] = {0.f, 0.f, 0.f, 0.f};
#pragma unroll
    for (int ks = 0; ks < 2; ++ks) {
        int row = l & 15;
        int cch = ks*4 + (l >> 4);
        int byte = row*128 + ((cch ^ (row & 7)) << 4);
        f16x8 pa = *(const f16x8*)((const char*)pw + byte);
#pragma unroll
        for (int nf = 0; nf < 16; ++nf) {
            f16x8 bf = *(const f16x8*)(vh + (nf*16 + (l & 15))*64 + ks*32 + (l >> 4)*8);
            o[nf] = mfma16(pa, bf, o[nf]);
        }
    }

#pragma unroll
    for (int rg = 0; rg < 4; ++rg) {
        int fo = qr0 + (l >> 4)*4 + rg;
#pragma unroll
        for (int nf = 0; nf < 16; ++nf) {
            int c = nf*16 + (l & 15);
            float v = o[nf][rg] * inv[rg] * beta[((size_t)(b*T_ + t)*64 + fo)*256 + c];
            fused[((size_t)(b*TP + t + 1)*FP + (fo + 1))*768 + 256 + c] = (f16)v;
        }
    }
}

// ---------------------------------------------------------------------------
// conv_final: implicit GEMM with fused-halo reuse (r7, unchanged).
// ---------------------------------------------------------------------------
__global__ __launch_bounds__(256, 2) void conv_final(
    const f16* __restrict__ fused, const f16* __restrict__ wfT,
    const float* __restrict__ biasF, float* __restrict__ out)
{
    __shared__ f16 smemH[288*64];     // 36 KB halo
    __shared__ f16 smemB[2][64*64];   // 16 KB B double-buffer

    const int mt = blockIdx.x;        // 0..249
    const int bb = mt / 125;
    const int t0 = (mt - bb*125) * 2; // 0..248
    const int Gs66 = (bb*TP + t0) * 66;

    const int tid = threadIdx.x;
    const int l   = tid & 63;
    const int wid = tid >> 6;
    const int wm = wid >> 1, wn = wid & 1;

    int hOff[9];
#pragma unroll
    for (int j = 0; j < 9; ++j) {
        int ps = j*32 + (tid >> 3);
        if (ps > 263) ps = 263;
        { int pm = XPOS - 1 - (bb*TP + t0)*66; if (ps > pm) ps = pm; }
        int ch = (tid & 7) ^ (ps & 7);
        hOff[j] = (Gs66 + ps)*768 + ch*8;
    }
    int bSrc[2];
#pragma unroll
    for (int j = 0; j < 2; ++j) {
        int row = j*32 + (tid >> 3);
        int ch  = (tid & 7) ^ (row & 7);
        bSrc[j] = row*768 + ch*8;
    }

    int pos00[4];
#pragma unroll
    for (int m = 0; m < 4; ++m) {
        int r = wm*64 + m*16 + (l & 15);      // 0..127
        pos00[m] = ((r >> 6) + 1)*66 + (r & 63) + 1;
    }
    int bRow[2], bSw[2];
#pragma unroll
    for (int n = 0; n < 2; ++n) {
        int row = wn*32 + n*16 + (l & 15);
        bRow[n] = row*64; bSw[n] = row & 7;
    }

    f32x4 acc[4][2];
#pragma unroll
    for (int m = 0; m < 4; ++m)
#pragma unroll
        for (int n = 0; n < 2; ++n) acc[m][n] = {0.f, 0.f, 0.f, 0.f};

#define FHSTAGE(C) do {                                                        \
        _Pragma("unroll")                                                      \
        for (int j_ = 0; j_ < 9; ++j_)                                         \
            gl_lds16(fused + hOff[j_] + (C)*64,                                \
                     smemH + (j_*256 + wid*64)*8);                             \
    } while (0)

#define FBSTAGE(TAP, C, NB) do {                                               \
        const f16* wt_ = wfT + (size_t)(TAP)*(64*768) + (C)*64;                \
        _Pragma("unroll")                                                      \
        for (int j_ = 0; j_ < 2; ++j_)                                         \
            gl_lds16(wt_ + bSrc[j_], &smemB[NB][(j_*256 + wid*64)*8]);         \
    } while (0)

#define FCOMP(NB, TAPOFF) do {                                                 \
        int pos_[4];                                                           \
        _Pragma("unroll")                                                      \
        for (int m = 0; m < 4; ++m) pos_[m] = pos00[m] + (TAPOFF);             \
        _Pragma("unroll")                                                      \
        for (int kk = 0; kk < 2; ++kk) {                                       \
            const int cch = kk*4 + (l >> 4);                                   \
            f16x8 af[4], bf[2];                                                \
            _Pragma("unroll")                                                  \
            for (int m = 0; m < 4; ++m)                                        \
                af[m] = *(const f16x8*)(smemH + pos_[m]*64 + ((cch ^ (pos_[m] & 7)) << 3)); \
            _Pragma("unroll")                                                  \
            for (int n = 0; n < 2; ++n)                                        \
                bf[n] = *(const f16x8*)(&smemB[NB][0] + bRow[n] + ((cch ^ bSw[n]) << 3)); \
            __builtin_amdgcn_s_setprio(1);                                     \
            _Pragma("unroll")                                                  \
            for (int m = 0; m < 4; ++m)                                        \
                _Pragma("unroll")                                              \
                for (int n = 0; n < 2; ++n)                                    \
                    acc[m][n] = mfma16(af[m], bf[n], acc[m][n]);               \
            __builtin_amdgcn_s_setprio(0);                                     \
        }                                                                      \
    } while (0)

    int buf = 0;
    FHSTAGE(0);
    FBSTAGE(0, 0, 0);
    __syncthreads();
    for (int c = 0; c < 12; ++c) {
        for (int tap = 0; tap < 9; ++tap) {
            if (tap < 8)       FBSTAGE(tap + 1, c, buf ^ 1);
            else if (c < 11)   FBSTAGE(0, c + 1, buf ^ 1);
            const int dt = tap/3 - 1, df = tap - (tap/3)*3 - 1;
            FCOMP(buf, dt*66 + df);
            __syncthreads();
            buf ^= 1;
        }
        if (c < 11) {
            FHSTAGE(c + 1);
            __syncthreads();
        }
    }
#undef FHSTAGE
#undef FBSTAGE
#undef FCOMP

#pragma unroll
    for (int m = 0; m < 4; ++m) {
#pragma unroll
        for (int rg = 0; rg < 4; ++rg) {
            int r = wm*64 + m*16 + (l >> 4)*4 + rg;      // D: row=(l>>4)*4+reg
            int t = t0 + (r >> 6), f = r & 63;
            if (t <= 248) {
                size_t pix = (size_t)bb*PIXB + t*64 + f;
#pragma unroll
                for (int n = 0; n < 2; ++n) {
                    int oc = wn*32 + n*16 + (l & 15);    // D: col=l&15
                    out[pix*64 + oc] = acc[m][n][rg] + biasF[oc];
                }
            }
        }
    }
}

// ---------------------------------------------------------------------------
extern "C" void kernel_launch(void* const* d_in, const int* in_sizes, int n_in,
                              void* d_out, int out_size, void* d_ws, size_t ws_size,
                              hipStream_t stream) {
    (void)in_sizes; (void)n_in; (void)out_size;
    const float* x    = (const float*)d_in[0];
    const float* wqf  = (const float*)d_in[1];
    const float* bqf  = (const float*)d_in[2];
    const float* wkf  = (const float*)d_in[3];
    const float* bkf  = (const float*)d_in[4];
    const float* wvf  = (const float*)d_in[5];
    const float* bvf  = (const float*)d_in[6];
    const float* wqt  = (const float*)d_in[7];
    const float* bqt  = (const float*)d_in[8];
    const float* wkt  = (const float*)d_in[9];
    const float* bkt  = (const float*)d_in[10];
    const float* wvt  = (const float*)d_in[11];
    const float* bvt  = (const float*)d_in[12];
    const float* wfin = (const float*)d_in[13];
    const float* bfin = (const float*)d_in[14];
    const float* alpha= (const float*)d_in[15];
    const float* beta = (const float*)d_in[16];

    if (ws_size < WS_NEED) return;   // workspace insufficient -> visible failure

    char* ws = (char*)d_ws;
    f16* fused  = (f16*)(ws + OFF_FUSED);
    f16* xpad   = (f16*)(ws + OFF_XPAD);
    f16* qf     = (f16*)(ws + OFF_QF);
    f16* kf     = (f16*)(ws + OFF_KF);
    f16* vf     = (f16*)(ws + OFF_VF);
    f16* qt     = (f16*)(ws + OFF_QT);
    f16* kt     = (f16*)(ws + OFF_KT);
    f16* vt     = (f16*)(ws + OFF_VT);
    f16* wT     = (f16*)(ws + OFF_WT);
    f16* wfT    = (f16*)(ws + OFF_WFT);
    float* bAll = (float*)(ws + OFF_BALL);
    float* bF   = (float*)(ws + OFF_BF);

    border_zero<<<dim3(630), dim3(256), 0, stream>>>(xpad, fused);
    vf_pad<<<dim3(128), dim3(256), 0, stream>>>(vf);
    prep_wT<<<dim3(216), dim3(256), 0, stream>>>(wqf, wkf, wvf, wqt, wkt, wvt, wT);
    prep_wmisc<<<dim3(1728), dim3(256), 0, stream>>>(
        wfin, bqf, bkf, bvf, bqt, bkt, bvt, bfin, wfT, bAll, bF);
    prep_x<<<dim3(NPIX*32/256), dim3(256), 0, stream>>>(x, xpad, fused);
    conv_qkv<<<dim3(1008), dim3(512), 0, stream>>>(xpad, wT, bAll, qf, kf, vf, qt, kt, vt);
    attn_f<<<dim3(512), dim3(256), 0, stream>>>(qf, kf, vf, alpha, fused);
    attn_t<<<dim3(498), dim3(256), 0, stream>>>(qt, kt, vt, beta, fused);
    conv_final<<<dim3(250), dim3(256), 0, stream>>>(fused, wfT, bF, (float*)d_out);
}